// Round 1
// baseline (868.626 us; speedup 1.0000x reference)
//
#include <hip/hip_runtime.h>
#include <hip/hip_bf16.h>
#include <stdint.h>

// Problem constants (N=8192 rows, C=4096 classes; reduction dim of joint GEMM = N)
#define NROWS 8192
#define CDIM  4096
#define KDIM  8192
#define EPS   1e-12f

typedef __attribute__((ext_vector_type(8))) short bf16x8;   // 8 bf16 in 4 VGPRs
typedef __attribute__((ext_vector_type(4))) float f32x4;

__device__ inline float wave_sum(float v) {
#pragma unroll
    for (int o = 32; o > 0; o >>= 1) v += __shfl_down(v, o, 64);
    return v;
}
__device__ inline float wave_max(float v) {
#pragma unroll
    for (int o = 32; o > 0; o >>= 1) v = fmaxf(v, __shfl_down(v, o, 64));
    return v;
}
// bf16 round-to-nearest-even (inputs are positive finite probs, no NaN handling needed)
__device__ inline unsigned short f2bf(float f) {
    unsigned int u = __float_as_uint(f);
    u += 0x7fffu + ((u >> 16) & 1u);
    return (unsigned short)(u >> 16);
}
__device__ inline float bf2f(unsigned short b) {
    return __uint_as_float(((unsigned int)b) << 16);
}

// ---------------------------------------------------------------------------
// Kernel 1: per-row softmax stats (max, lnZ) + entropy accumulation.
// entropy_n = max + lnZ - (sum e^{x-max} * x)/Z   (no per-element log needed)
// ---------------------------------------------------------------------------
__global__ __launch_bounds__(256) void row_stats_kernel(const float* __restrict__ X,
                                                        float2* __restrict__ stats,
                                                        float* __restrict__ ent_acc) {
    __shared__ float sred[8];
    const int t = threadIdx.x;
    const int lane = t & 63, w = t >> 6;
    const float* row = X + (size_t)blockIdx.x * CDIM;
    float4 xv[4];
#pragma unroll
    for (int s = 0; s < 4; s++) xv[s] = ((const float4*)row)[s * 256 + t];
    float m = -3.0e38f;
#pragma unroll
    for (int s = 0; s < 4; s++)
        m = fmaxf(m, fmaxf(fmaxf(xv[s].x, xv[s].y), fmaxf(xv[s].z, xv[s].w)));
    m = wave_max(m);
    if (lane == 0) sred[w] = m;
    __syncthreads();
    const float bm = fmaxf(fmaxf(sred[0], sred[1]), fmaxf(sred[2], sred[3]));
    float Z = 0.f, S = 0.f;
#pragma unroll
    for (int s = 0; s < 4; s++) {
        float e;
        e = __expf(xv[s].x - bm); Z += e; S += e * xv[s].x;
        e = __expf(xv[s].y - bm); Z += e; S += e * xv[s].y;
        e = __expf(xv[s].z - bm); Z += e; S += e * xv[s].z;
        e = __expf(xv[s].w - bm); Z += e; S += e * xv[s].w;
    }
    __syncthreads();   // sred reuse
    Z = wave_sum(Z); S = wave_sum(S);
    if (lane == 0) { sred[w] = Z; sred[4 + w] = S; }
    __syncthreads();
    if (t == 0) {
        float Zt = sred[0] + sred[1] + sred[2] + sred[3];
        float St = sred[4] + sred[5] + sred[6] + sred[7];
        float lnZ = __logf(Zt);
        stats[blockIdx.x] = make_float2(bm, lnZ);
        atomicAdd(ent_acc, bm + lnZ - St / Zt);
    }
}

// ---------------------------------------------------------------------------
// Kernel 2: normalize (p = e^{x-max-lnZ}), cast to bf16, 64x64 LDS transpose
// to [C][N] layout, plus fp32 column-sum partials for the margins (computed
// from the bf16-rounded values so marg & joint share the same quantization).
// ---------------------------------------------------------------------------
#define TSTRIDE 68
__global__ __launch_bounds__(256) void norm_transpose_kernel(const float* __restrict__ X,
                                                             const float2* __restrict__ stats,
                                                             unsigned short* __restrict__ XT,
                                                             float* __restrict__ marg) {
    __shared__ __align__(16) unsigned short tile[64 * TSTRIDE];
    __shared__ float smarg[64];
    __shared__ float2 sst[64];
    const int t = threadIdx.x;
    const int c0 = blockIdx.x * 64, n0 = blockIdx.y * 64;
    if (t < 64) { sst[t] = stats[n0 + t]; smarg[t] = 0.f; }
    __syncthreads();
    const int cq = (t & 15) * 4;   // col within tile (x4)
    const int r0 = t >> 4;         // row group
    float p0 = 0.f, p1 = 0.f, p2 = 0.f, p3 = 0.f;
#pragma unroll
    for (int s = 0; s < 4; s++) {
        int r = s * 16 + r0;
        float2 st = sst[r];
        float4 x = *(const float4*)(X + (size_t)(n0 + r) * CDIM + c0 + cq);
        unsigned short b0 = f2bf(__expf(x.x - st.x - st.y));
        unsigned short b1 = f2bf(__expf(x.y - st.x - st.y));
        unsigned short b2 = f2bf(__expf(x.z - st.x - st.y));
        unsigned short b3 = f2bf(__expf(x.w - st.x - st.y));
        p0 += bf2f(b0); p1 += bf2f(b1); p2 += bf2f(b2); p3 += bf2f(b3);
        uint2 pk;
        pk.x = (unsigned)b0 | ((unsigned)b1 << 16);
        pk.y = (unsigned)b2 | ((unsigned)b3 << 16);
        *(uint2*)&tile[r * TSTRIDE + cq] = pk;
    }
    atomicAdd(&smarg[cq + 0], p0);
    atomicAdd(&smarg[cq + 1], p1);
    atomicAdd(&smarg[cq + 2], p2);
    atomicAdd(&smarg[cq + 3], p3);
    __syncthreads();
    const int cc = t >> 3;         // 0..31 output row (class) within tile
    const int nb = (t & 7) * 8;    // n chunk
#pragma unroll
    for (int s = 0; s < 2; s++) {
        int c = s * 32 + cc;
        uint4 o;
        unsigned v0, v1;
        v0 = tile[(nb + 0) * TSTRIDE + c]; v1 = tile[(nb + 1) * TSTRIDE + c]; o.x = v0 | (v1 << 16);
        v0 = tile[(nb + 2) * TSTRIDE + c]; v1 = tile[(nb + 3) * TSTRIDE + c]; o.y = v0 | (v1 << 16);
        v0 = tile[(nb + 4) * TSTRIDE + c]; v1 = tile[(nb + 5) * TSTRIDE + c]; o.z = v0 | (v1 << 16);
        v0 = tile[(nb + 6) * TSTRIDE + c]; v1 = tile[(nb + 7) * TSTRIDE + c]; o.w = v0 | (v1 << 16);
        *(uint4*)(XT + (size_t)(c0 + c) * KDIM + n0 + nb) = o;
    }
    if (t < 64) atomicAdd(&marg[c0 + t], smarg[t]);
}

// ---------------------------------------------------------------------------
// Kernel 3: joint GEMM (m97-style 128x128 bf16 "BT" GEMM: both operands [4096][8192]
// K-contiguous) fused with the MI epilogue Σ j*log(j+eps); joint never stored.
// ---------------------------------------------------------------------------
#define GLD16(g, l)                                                                   \
    __builtin_amdgcn_global_load_lds((const __attribute__((address_space(1))) unsigned int*)(g), \
                                     (__attribute__((address_space(3))) unsigned int*)(l), 16, 0, 0)

__global__ __launch_bounds__(256) void gemm_mi_kernel(const unsigned short* __restrict__ A,
                                                      const unsigned short* __restrict__ B,
                                                      float* __restrict__ S_out) {
    __shared__ __align__(16) unsigned short As[128 * 32];
    __shared__ __align__(16) unsigned short Bs[128 * 32];
    const int t = threadIdx.x;
    const int m0 = blockIdx.x * 128, n0 = blockIdx.y * 128;
    // staging: thread t moves 16B; LDS fill order == lane*16 (global_load_lds rule)
    const int sr = t >> 2;          // row 0..63
    const int sk = (t & 3) * 8;     // k element offset
    const unsigned short* ga0 = A + (size_t)(m0 + sr) * KDIM + sk;
    const unsigned short* ga1 = ga0 + (size_t)64 * KDIM;
    const unsigned short* gb0 = B + (size_t)(n0 + sr) * KDIM + sk;
    const unsigned short* gb1 = gb0 + (size_t)64 * KDIM;
    unsigned short* lA0 = &As[t * 8];
    unsigned short* lA1 = &As[2048 + t * 8];
    unsigned short* lB0 = &Bs[t * 8];
    unsigned short* lB1 = &Bs[2048 + t * 8];
    const int lane = t & 63, wave = t >> 6;
    const int wm = (wave & 1) * 64, wn = (wave >> 1) * 64;
    const int fr = lane & 15, quad = lane >> 4;
    const unsigned short* pA = &As[(wm + fr) * 32 + quad * 8];
    const unsigned short* pB = &Bs[(wn + fr) * 32 + quad * 8];
    f32x4 acc[4][4];
    f32x4 zero = {0.f, 0.f, 0.f, 0.f};
#pragma unroll
    for (int i = 0; i < 4; i++)
#pragma unroll
        for (int j = 0; j < 4; j++) acc[i][j] = zero;

    for (int k0 = 0; k0 < KDIM; k0 += 32) {
        GLD16(ga0 + k0, lA0);
        GLD16(ga1 + k0, lA1);
        GLD16(gb0 + k0, lB0);
        GLD16(gb1 + k0, lB1);
        __syncthreads();   // drains vmcnt before barrier (m97 semantics)
        bf16x8 af[4], bg[4];
#pragma unroll
        for (int i = 0; i < 4; i++) af[i] = *(const bf16x8*)(pA + i * 512);
#pragma unroll
        for (int j = 0; j < 4; j++) bg[j] = *(const bf16x8*)(pB + j * 512);
#pragma unroll
        for (int i = 0; i < 4; i++)
#pragma unroll
            for (int j = 0; j < 4; j++)
                acc[i][j] = __builtin_amdgcn_mfma_f32_16x16x32_bf16(af[i], bg[j], acc[i][j], 0, 0, 0);
        __syncthreads();
    }
    // epilogue: j = acc/N; sum j*log(j+eps). Sum over all elements -> layout-invariant.
    const float invN = 1.0f / 8192.0f;
    float loc = 0.f;
#pragma unroll
    for (int i = 0; i < 4; i++)
#pragma unroll
        for (int j = 0; j < 4; j++)
#pragma unroll
            for (int r = 0; r < 4; r++) {
                float v = acc[i][j][r] * invN;
                loc += v * __logf(v + EPS);
            }
    loc = wave_sum(loc);
    __shared__ float sred[4];
    if (lane == 0) sred[wave] = loc;
    __syncthreads();
    if (t == 0) atomicAdd(S_out, sred[0] + sred[1] + sred[2] + sred[3]);
}

// ---------------------------------------------------------------------------
// Kernel 4: finalize. MI = S_jlogj - Σ mX log(mX+eps) - Σ mY log(mY+eps)
// ---------------------------------------------------------------------------
__global__ __launch_bounds__(256) void finalize_kernel(const float* __restrict__ accums,
                                                       const float* __restrict__ margX,
                                                       const float* __restrict__ margY,
                                                       float* __restrict__ out) {
    const int t = threadIdx.x;
    const int lane = t & 63, w = t >> 6;
    const float invN = 1.0f / 8192.0f;
    float sx = 0.f, sy = 0.f;
    for (int c = t; c < CDIM; c += 256) {
        float mx = margX[c] * invN;
        float my = margY[c] * invN;
        sx += mx * __logf(mx + EPS);
        sy += my * __logf(my + EPS);
    }
    sx = wave_sum(sx); sy = wave_sum(sy);
    __shared__ float rx[4], ry[4];
    if (lane == 0) { rx[w] = sx; ry[w] = sy; }
    __syncthreads();
    if (t == 0) {
        float SX = rx[0] + rx[1] + rx[2] + rx[3];
        float SY = ry[0] + ry[1] + ry[2] + ry[3];
        out[0] = accums[0] * invN;          // mean entropy
        out[1] = accums[1] - SX - SY;       // MI
    }
}

// ---------------------------------------------------------------------------
// Workspace layout (bytes):
//   0         PXT  bf16 [4096][8192]   67108864
//   67108864  PYT  bf16 [4096][8192]   67108864
//   134217728 statsX float2[8192]         65536
//   134283264 statsY float2[8192]         65536
//   134348800 margX  f32[4096]            16384
//   134365184 margY  f32[4096]            16384
//   134381568 accums f32[0]=ent_sum [1]=S_jlogj [2]=ent_dummy
// ---------------------------------------------------------------------------
extern "C" void kernel_launch(void* const* d_in, const int* in_sizes, int n_in,
                              void* d_out, int out_size, void* d_ws, size_t ws_size,
                              hipStream_t stream) {
    const float* X = (const float*)d_in[0];
    const float* Y = (const float*)d_in[1];
    char* ws = (char*)d_ws;
    unsigned short* PXT = (unsigned short*)ws;
    unsigned short* PYT = (unsigned short*)(ws + 67108864ll);
    float2* statsX = (float2*)(ws + 134217728ll);
    float2* statsY = (float2*)(ws + 134283264ll);
    float* margX = (float*)(ws + 134348800ll);
    float* margY = (float*)(ws + 134365184ll);
    float* accums = (float*)(ws + 134381568ll);

    // zero margins + accumulators (ws is poisoned 0xAA before every launch)
    hipMemsetAsync(ws + 134348800ll, 0, 2 * 16384 + 256, stream);

    row_stats_kernel<<<NROWS, 256, 0, stream>>>(X, statsX, &accums[0]);
    row_stats_kernel<<<NROWS, 256, 0, stream>>>(Y, statsY, &accums[2]);   // entropy discarded
    norm_transpose_kernel<<<dim3(CDIM / 64, NROWS / 64), 256, 0, stream>>>(X, statsX, PXT, margX);
    norm_transpose_kernel<<<dim3(CDIM / 64, NROWS / 64), 256, 0, stream>>>(Y, statsY, PYT, margY);
    gemm_mi_kernel<<<dim3(CDIM / 128, CDIM / 128), 256, 0, stream>>>(PXT, PYT, &accums[1]);
    finalize_kernel<<<1, 256, 0, stream>>>(accums, margX, margY, (float*)d_out);
}

// Round 2
// 736.591 us; speedup vs baseline: 1.1793x; 1.1793x over previous
//
#include <hip/hip_runtime.h>
#include <hip/hip_bf16.h>
#include <stdint.h>

// Problem constants (N=8192 rows, C=4096 classes; reduction dim of joint GEMM = N)
#define NROWS 8192
#define CDIM  4096
#define KDIM  8192
#define EPS   1e-12f

typedef __attribute__((ext_vector_type(8))) short bf16x8;   // 8 bf16 in 4 VGPRs
typedef __attribute__((ext_vector_type(4))) float f32x4;

// Butterfly reductions: all lanes end with the result (no broadcast needed).
__device__ inline float wave_sum(float v) {
#pragma unroll
    for (int o = 32; o > 0; o >>= 1) v += __shfl_xor(v, o, 64);
    return v;
}
__device__ inline float wave_max(float v) {
#pragma unroll
    for (int o = 32; o > 0; o >>= 1) v = fmaxf(v, __shfl_xor(v, o, 64));
    return v;
}
// bf16 round-to-nearest-even (inputs are positive finite probs, no NaN handling needed)
__device__ inline unsigned short f2bf(float f) {
    unsigned int u = __float_as_uint(f);
    u += 0x7fffu + ((u >> 16) & 1u);
    return (unsigned short)(u >> 16);
}
__device__ inline float bf2f(unsigned short b) {
    return __uint_as_float(((unsigned int)b) << 16);
}

// ---------------------------------------------------------------------------
// Kernel 1: per-row softmax stats (max, lnZ) + entropy, one WAVE per row.
// Row (4096 f32 = 16 KB) held in 64 VGPRs/lane; butterfly reductions only —
// no __syncthreads in the hot path, NO single-address device atomics
// (that was Round-1's serialization bug: 2x8192 LLC atomics to one word).
// entropy_n = max + lnZ - (sum e^{x-max} * x)/Z   (no per-element log needed)
// grid = (2048, 2): y=0 -> X (entropy kept), y=1 -> Y.
// ---------------------------------------------------------------------------
__global__ __launch_bounds__(256) void row_stats_kernel(const float* __restrict__ X,
                                                        const float* __restrict__ Y,
                                                        float2* __restrict__ statsX,
                                                        float2* __restrict__ statsY,
                                                        float* __restrict__ entPart) {
    const int t = threadIdx.x, lane = t & 63, wave = t >> 6;
    const int row = blockIdx.x * 4 + wave;
    const bool isY = blockIdx.y != 0;
    const float4* s4 = (const float4*)((isY ? Y : X) + (size_t)row * CDIM);
    float4 v[16];
#pragma unroll
    for (int i = 0; i < 16; i++) v[i] = s4[i * 64 + lane];
    float m = -3.0e38f;
#pragma unroll
    for (int i = 0; i < 16; i++)
        m = fmaxf(m, fmaxf(fmaxf(v[i].x, v[i].y), fmaxf(v[i].z, v[i].w)));
    m = wave_max(m);
    float Z = 0.f, S = 0.f;
#pragma unroll
    for (int i = 0; i < 16; i++) {
        float e;
        e = __expf(v[i].x - m); Z += e; S += e * v[i].x;
        e = __expf(v[i].y - m); Z += e; S += e * v[i].y;
        e = __expf(v[i].z - m); Z += e; S += e * v[i].z;
        e = __expf(v[i].w - m); Z += e; S += e * v[i].w;
    }
    Z = wave_sum(Z); S = wave_sum(S);
    __shared__ float sent[4];
    if (lane == 0) {
        float lnZ = __logf(Z);
        (isY ? statsY : statsX)[row] = make_float2(m, lnZ);
        sent[wave] = m + lnZ - S / Z;
    }
    __syncthreads();
    if (t == 0 && !isY)
        entPart[blockIdx.x] = sent[0] + sent[1] + sent[2] + sent[3];
}

// ---------------------------------------------------------------------------
// Kernel 2: normalize (p = e^{x-max-lnZ}), cast to bf16, 64x64 LDS transpose
// to [C][N] layout, plus fp32 column-sum partials for the margins (computed
// from the bf16-rounded values so marg & joint share the same quantization).
// grid = (64, 128, 2): z selects X/Y.
// ---------------------------------------------------------------------------
#define TSTRIDE 68
__global__ __launch_bounds__(256) void norm_transpose_kernel(
        const float* __restrict__ Xg, const float* __restrict__ Yg,
        const float2* __restrict__ statsX, const float2* __restrict__ statsY,
        unsigned short* __restrict__ PXT, unsigned short* __restrict__ PYT,
        float* __restrict__ margX, float* __restrict__ margY) {
    const bool isY = blockIdx.z != 0;
    const float* __restrict__ X = isY ? Yg : Xg;
    const float2* __restrict__ stats = isY ? statsY : statsX;
    unsigned short* __restrict__ XT = isY ? PYT : PXT;
    float* __restrict__ marg = isY ? margY : margX;

    __shared__ __align__(16) unsigned short tile[64 * TSTRIDE];
    __shared__ float smarg[64];
    __shared__ float2 sst[64];
    const int t = threadIdx.x;
    const int c0 = blockIdx.x * 64, n0 = blockIdx.y * 64;
    if (t < 64) { sst[t] = stats[n0 + t]; smarg[t] = 0.f; }
    __syncthreads();
    const int cq = (t & 15) * 4;   // col within tile (x4)
    const int r0 = t >> 4;         // row group
    float p0 = 0.f, p1 = 0.f, p2 = 0.f, p3 = 0.f;
#pragma unroll
    for (int s = 0; s < 4; s++) {
        int r = s * 16 + r0;
        float2 st = sst[r];
        float4 x = *(const float4*)(X + (size_t)(n0 + r) * CDIM + c0 + cq);
        unsigned short b0 = f2bf(__expf(x.x - st.x - st.y));
        unsigned short b1 = f2bf(__expf(x.y - st.x - st.y));
        unsigned short b2 = f2bf(__expf(x.z - st.x - st.y));
        unsigned short b3 = f2bf(__expf(x.w - st.x - st.y));
        p0 += bf2f(b0); p1 += bf2f(b1); p2 += bf2f(b2); p3 += bf2f(b3);
        uint2 pk;
        pk.x = (unsigned)b0 | ((unsigned)b1 << 16);
        pk.y = (unsigned)b2 | ((unsigned)b3 << 16);
        *(uint2*)&tile[r * TSTRIDE + cq] = pk;
    }
    atomicAdd(&smarg[cq + 0], p0);
    atomicAdd(&smarg[cq + 1], p1);
    atomicAdd(&smarg[cq + 2], p2);
    atomicAdd(&smarg[cq + 3], p3);
    __syncthreads();
    const int cc = t >> 3;         // 0..31 output row (class) within tile
    const int nb = (t & 7) * 8;    // n chunk
#pragma unroll
    for (int s = 0; s < 2; s++) {
        int c = s * 32 + cc;
        uint4 o;
        unsigned v0, v1;
        v0 = tile[(nb + 0) * TSTRIDE + c]; v1 = tile[(nb + 1) * TSTRIDE + c]; o.x = v0 | (v1 << 16);
        v0 = tile[(nb + 2) * TSTRIDE + c]; v1 = tile[(nb + 3) * TSTRIDE + c]; o.y = v0 | (v1 << 16);
        v0 = tile[(nb + 4) * TSTRIDE + c]; v1 = tile[(nb + 5) * TSTRIDE + c]; o.z = v0 | (v1 << 16);
        v0 = tile[(nb + 6) * TSTRIDE + c]; v1 = tile[(nb + 7) * TSTRIDE + c]; o.w = v0 | (v1 << 16);
        *(uint4*)(XT + (size_t)(c0 + c) * KDIM + n0 + nb) = o;
    }
    // 524k atomics spread over 4096 addresses (128/address) — parallel across
    // TCC channels, unlike the single-address entropy atomic. Keep.
    if (t < 64) atomicAdd(&marg[c0 + t], smarg[t]);
}

// ---------------------------------------------------------------------------
// Kernel 3: joint GEMM (m97-style 128x128 bf16 "BT" GEMM: both operands [4096][8192]
// K-contiguous) fused with the MI epilogue Σ j*log(j+eps); joint never stored.
// ---------------------------------------------------------------------------
#define GLD16(g, l)                                                                   \
    __builtin_amdgcn_global_load_lds((const __attribute__((address_space(1))) unsigned int*)(g), \
                                     (__attribute__((address_space(3))) unsigned int*)(l), 16, 0, 0)

__global__ __launch_bounds__(256) void gemm_mi_kernel(const unsigned short* __restrict__ A,
                                                      const unsigned short* __restrict__ B,
                                                      float* __restrict__ S_out) {
    __shared__ __align__(16) unsigned short As[128 * 32];
    __shared__ __align__(16) unsigned short Bs[128 * 32];
    const int t = threadIdx.x;
    const int m0 = blockIdx.x * 128, n0 = blockIdx.y * 128;
    // staging: thread t moves 16B; LDS fill order == lane*16 (global_load_lds rule)
    const int sr = t >> 2;          // row 0..63
    const int sk = (t & 3) * 8;     // k element offset
    const unsigned short* ga0 = A + (size_t)(m0 + sr) * KDIM + sk;
    const unsigned short* ga1 = ga0 + (size_t)64 * KDIM;
    const unsigned short* gb0 = B + (size_t)(n0 + sr) * KDIM + sk;
    const unsigned short* gb1 = gb0 + (size_t)64 * KDIM;
    unsigned short* lA0 = &As[t * 8];
    unsigned short* lA1 = &As[2048 + t * 8];
    unsigned short* lB0 = &Bs[t * 8];
    unsigned short* lB1 = &Bs[2048 + t * 8];
    const int lane = t & 63, wave = t >> 6;
    const int wm = (wave & 1) * 64, wn = (wave >> 1) * 64;
    const int fr = lane & 15, quad = lane >> 4;
    const unsigned short* pA = &As[(wm + fr) * 32 + quad * 8];
    const unsigned short* pB = &Bs[(wn + fr) * 32 + quad * 8];
    f32x4 acc[4][4];
    f32x4 zero = {0.f, 0.f, 0.f, 0.f};
#pragma unroll
    for (int i = 0; i < 4; i++)
#pragma unroll
        for (int j = 0; j < 4; j++) acc[i][j] = zero;

    for (int k0 = 0; k0 < KDIM; k0 += 32) {
        GLD16(ga0 + k0, lA0);
        GLD16(ga1 + k0, lA1);
        GLD16(gb0 + k0, lB0);
        GLD16(gb1 + k0, lB1);
        __syncthreads();   // drains vmcnt before barrier (m97 semantics)
        bf16x8 af[4], bg[4];
#pragma unroll
        for (int i = 0; i < 4; i++) af[i] = *(const bf16x8*)(pA + i * 512);
#pragma unroll
        for (int j = 0; j < 4; j++) bg[j] = *(const bf16x8*)(pB + j * 512);
#pragma unroll
        for (int i = 0; i < 4; i++)
#pragma unroll
            for (int j = 0; j < 4; j++)
                acc[i][j] = __builtin_amdgcn_mfma_f32_16x16x32_bf16(af[i], bg[j], acc[i][j], 0, 0, 0);
        __syncthreads();
    }
    // epilogue: j = acc/N; sum j*log(j+eps). Sum over all elements -> layout-invariant.
    const float invN = 1.0f / 8192.0f;
    float loc = 0.f;
#pragma unroll
    for (int i = 0; i < 4; i++)
#pragma unroll
        for (int j = 0; j < 4; j++)
#pragma unroll
            for (int r = 0; r < 4; r++) {
                float v = acc[i][j][r] * invN;
                loc += v * __logf(v + EPS);
            }
    loc = wave_sum(loc);
    __shared__ float sred[4];
    if (lane == 0) sred[wave] = loc;
    __syncthreads();
    if (t == 0) atomicAdd(S_out, sred[0] + sred[1] + sred[2] + sred[3]);
}

// ---------------------------------------------------------------------------
// Kernel 4: finalize. entropy = Σ entPart / N;
// MI = S_jlogj - Σ mX log(mX+eps) - Σ mY log(mY+eps)
// ---------------------------------------------------------------------------
__global__ __launch_bounds__(256) void finalize_kernel(const float* __restrict__ accums,
                                                       const float* __restrict__ entPart,
                                                       const float* __restrict__ margX,
                                                       const float* __restrict__ margY,
                                                       float* __restrict__ out) {
    const int t = threadIdx.x;
    const int lane = t & 63, w = t >> 6;
    const float invN = 1.0f / 8192.0f;
    float sx = 0.f, sy = 0.f, se = 0.f;
    for (int c = t; c < CDIM; c += 256) {
        float mx = margX[c] * invN;
        float my = margY[c] * invN;
        sx += mx * __logf(mx + EPS);
        sy += my * __logf(my + EPS);
    }
    for (int c = t; c < 2048; c += 256) se += entPart[c];
    sx = wave_sum(sx); sy = wave_sum(sy); se = wave_sum(se);
    __shared__ float rx[4], ry[4], re[4];
    if (lane == 0) { rx[w] = sx; ry[w] = sy; re[w] = se; }
    __syncthreads();
    if (t == 0) {
        float SX = rx[0] + rx[1] + rx[2] + rx[3];
        float SY = ry[0] + ry[1] + ry[2] + ry[3];
        float SE = re[0] + re[1] + re[2] + re[3];
        out[0] = SE * invN;                 // mean entropy
        out[1] = accums[0] - SX - SY;       // MI
    }
}

// ---------------------------------------------------------------------------
// Workspace layout (bytes):
//   0         PXT  bf16 [4096][8192]   67108864
//   67108864  PYT  bf16 [4096][8192]   67108864
//   134217728 statsX float2[8192]         65536
//   134283264 statsY float2[8192]         65536
//   134348800 margX  f32[4096]            16384
//   134365184 margY  f32[4096]            16384
//   134381568 accums f32[0]=S_jlogj        256
//   134381824 entPart f32[2048]           8192
// ---------------------------------------------------------------------------
extern "C" void kernel_launch(void* const* d_in, const int* in_sizes, int n_in,
                              void* d_out, int out_size, void* d_ws, size_t ws_size,
                              hipStream_t stream) {
    const float* X = (const float*)d_in[0];
    const float* Y = (const float*)d_in[1];
    char* ws = (char*)d_ws;
    unsigned short* PXT = (unsigned short*)ws;
    unsigned short* PYT = (unsigned short*)(ws + 67108864ll);
    float2* statsX = (float2*)(ws + 134217728ll);
    float2* statsY = (float2*)(ws + 134283264ll);
    float* margX = (float*)(ws + 134348800ll);
    float* margY = (float*)(ws + 134365184ll);
    float* accums = (float*)(ws + 134381568ll);
    float* entPart = (float*)(ws + 134381824ll);

    // zero margins + accumulators (ws is poisoned 0xAA before every launch)
    hipMemsetAsync(ws + 134348800ll, 0, 2 * 16384 + 256, stream);

    row_stats_kernel<<<dim3(2048, 2), 256, 0, stream>>>(X, Y, statsX, statsY, entPart);
    norm_transpose_kernel<<<dim3(CDIM / 64, NROWS / 64, 2), 256, 0, stream>>>(
        X, Y, statsX, statsY, PXT, PYT, margX, margY);
    gemm_mi_kernel<<<dim3(CDIM / 128, CDIM / 128), 256, 0, stream>>>(PXT, PYT, &accums[0]);
    finalize_kernel<<<1, 256, 0, stream>>>(accums, entPart, margX, margY, (float*)d_out);
}

// Round 3
// 540.710 us; speedup vs baseline: 1.6065x; 1.3623x over previous
//
#include <hip/hip_runtime.h>
#include <hip/hip_bf16.h>
#include <stdint.h>

// Problem constants (N=8192 rows, C=4096 classes; reduction dim of joint GEMM = N)
#define NROWS 8192
#define CDIM  4096
#define KDIM  8192
#define EPS   1e-12f

typedef __attribute__((ext_vector_type(8)))  int   v8i;     // 32 fp8 bytes (8 VGPRs)
typedef __attribute__((ext_vector_type(16))) float f32x16;  // MFMA 32x32 acc
typedef __attribute__((ext_vector_type(2)))  float f32x2;

// Butterfly reductions: all lanes end with the result.
__device__ inline float wave_sum(float v) {
#pragma unroll
    for (int o = 32; o > 0; o >>= 1) v += __shfl_xor(v, o, 64);
    return v;
}
__device__ inline float wave_max(float v) {
#pragma unroll
    for (int o = 32; o > 0; o >>= 1) v = fmaxf(v, __shfl_xor(v, o, 64));
    return v;
}
// bf16 round-to-nearest-even (positive finite inputs only)
__device__ inline unsigned short f2bf(float f) {
    unsigned int u = __float_as_uint(f);
    u += 0x7fffu + ((u >> 16) & 1u);
    return (unsigned short)(u >> 16);
}
__device__ inline float bf2f(unsigned short b) {
    return __uint_as_float(((unsigned int)b) << 16);
}

// ---------------------------------------------------------------------------
// Kernel 1: per-row softmax stats (max, lnZ) + entropy, one WAVE per row.
// entropy_n = max + lnZ - (sum e^{x-max} * x)/Z. grid=(2048,2): y=1 -> Y.
// ---------------------------------------------------------------------------
__global__ __launch_bounds__(256) void row_stats_kernel(const float* __restrict__ X,
                                                        const float* __restrict__ Y,
                                                        float2* __restrict__ statsX,
                                                        float2* __restrict__ statsY,
                                                        float* __restrict__ entPart) {
    const int t = threadIdx.x, lane = t & 63, wave = t >> 6;
    const int row = blockIdx.x * 4 + wave;
    const bool isY = blockIdx.y != 0;
    const float4* s4 = (const float4*)((isY ? Y : X) + (size_t)row * CDIM);
    float4 v[16];
#pragma unroll
    for (int i = 0; i < 16; i++) v[i] = s4[i * 64 + lane];
    float m = -3.0e38f;
#pragma unroll
    for (int i = 0; i < 16; i++)
        m = fmaxf(m, fmaxf(fmaxf(v[i].x, v[i].y), fmaxf(v[i].z, v[i].w)));
    m = wave_max(m);
    float Z = 0.f, S = 0.f;
#pragma unroll
    for (int i = 0; i < 16; i++) {
        float e;
        e = __expf(v[i].x - m); Z += e; S += e * v[i].x;
        e = __expf(v[i].y - m); Z += e; S += e * v[i].y;
        e = __expf(v[i].z - m); Z += e; S += e * v[i].z;
        e = __expf(v[i].w - m); Z += e; S += e * v[i].w;
    }
    Z = wave_sum(Z); S = wave_sum(S);
    __shared__ float sent[4];
    if (lane == 0) {
        float lnZ = __logf(Z);
        (isY ? statsY : statsX)[row] = make_float2(m, lnZ);
        sent[wave] = m + lnZ - S / Z;
    }
    __syncthreads();
    if (t == 0 && !isY)
        entPart[blockIdx.x] = sent[0] + sent[1] + sent[2] + sent[3];
}

// ---------------------------------------------------------------------------
// Kernel 2: normalize (p = e^{x-max-lnZ}), 64x64 LDS transpose, quantize to
// fp8 e4m3 with x512 pre-scale (probs ~2.4e-4 sit below e4m3's subnormal
// floor 2^-9; 512*p ~ 0.125 lands in the normal range). Margins accumulated
// from the DEQUANTIZED fp8 values so marg & joint share quantization.
// grid = (64, 128, 2): z selects X/Y.
// ---------------------------------------------------------------------------
#define TSTRIDE 68
__global__ __launch_bounds__(256) void norm_transpose_kernel(
        const float* __restrict__ Xg, const float* __restrict__ Yg,
        const float2* __restrict__ statsX, const float2* __restrict__ statsY,
        unsigned char* __restrict__ PXT, unsigned char* __restrict__ PYT,
        float* __restrict__ margX, float* __restrict__ margY) {
    const bool isY = blockIdx.z != 0;
    const float* __restrict__ X = isY ? Yg : Xg;
    const float2* __restrict__ stats = isY ? statsY : statsX;
    unsigned char* __restrict__ XT = isY ? PYT : PXT;
    float* __restrict__ marg = isY ? margY : margX;

    __shared__ __align__(16) unsigned short tile[64 * TSTRIDE];  // bf16 staging
    __shared__ float smarg[64];
    __shared__ float2 sst[64];
    const int t = threadIdx.x;
    const int c0 = blockIdx.x * 64, n0 = blockIdx.y * 64;
    if (t < 64) { sst[t] = stats[n0 + t]; smarg[t] = 0.f; }
    __syncthreads();
    // phase 1: read + softmax-normalize + pack bf16 into [n][c] tile
    const int cq = (t & 15) * 4;   // col within tile (x4)
    const int r0 = t >> 4;         // row group
#pragma unroll
    for (int s = 0; s < 4; s++) {
        int r = s * 16 + r0;
        float2 st = sst[r];
        float4 x = *(const float4*)(X + (size_t)(n0 + r) * CDIM + c0 + cq);
        uint2 pk;
        pk.x = (unsigned)f2bf(__expf(x.x - st.x - st.y)) |
               ((unsigned)f2bf(__expf(x.y - st.x - st.y)) << 16);
        pk.y = (unsigned)f2bf(__expf(x.z - st.x - st.y)) |
               ((unsigned)f2bf(__expf(x.w - st.x - st.y)) << 16);
        *(uint2*)&tile[r * TSTRIDE + cq] = pk;
    }
    __syncthreads();
    // phase 2: transpose-read 16 n per thread for one class, quantize fp8,
    // store 16B, accumulate dequantized margin partial.
    const int cc = t >> 2;         // class 0..63
    const int ng = (t & 3) * 16;   // n chunk
    float msum = 0.f;
    uint4 o;
    unsigned int* ow = &o.x;
#pragma unroll
    for (int g = 0; g < 4; g++) {
        float f0 = 512.0f * bf2f(tile[(ng + g * 4 + 0) * TSTRIDE + cc]);
        float f1 = 512.0f * bf2f(tile[(ng + g * 4 + 1) * TSTRIDE + cc]);
        float f2 = 512.0f * bf2f(tile[(ng + g * 4 + 2) * TSTRIDE + cc]);
        float f3 = 512.0f * bf2f(tile[(ng + g * 4 + 3) * TSTRIDE + cc]);
        unsigned int wrd = (unsigned int)__builtin_amdgcn_cvt_pk_fp8_f32(f0, f1, 0, false);
        wrd = (unsigned int)__builtin_amdgcn_cvt_pk_fp8_f32(f2, f3, (int)wrd, true);
        ow[g] = wrd;
        f32x2 d0 = __builtin_amdgcn_cvt_pk_f32_fp8((int)wrd, false);
        f32x2 d1 = __builtin_amdgcn_cvt_pk_f32_fp8((int)wrd, true);
        msum += (d0.x + d0.y) + (d1.x + d1.y);
    }
    *(uint4*)(XT + (size_t)(c0 + cc) * KDIM + n0 + ng) = o;
    atomicAdd(&smarg[cc], msum);   // 4 threads/class, LDS atomic
    __syncthreads();
    if (t < 64) atomicAdd(&marg[c0 + t], smarg[t]);   // spread over 4096 addrs
}

// ---------------------------------------------------------------------------
// Kernel 3: joint GEMM in MX-fp8 (m148-class: mfma_scale 32x32x64 f8f6f4,
// scales = 1.0), both operands fp8 [4096][8192] K-contiguous, fused epilogue
// Σ j*log(j+eps); joint never stored. Epilogue is a global sum -> invariant
// to row/col permutation AND to consistent K-permutation of A/B fragments.
// ---------------------------------------------------------------------------
#define GLD16(g, l)                                                                   \
    __builtin_amdgcn_global_load_lds((const __attribute__((address_space(1))) unsigned int*)(g), \
                                     (__attribute__((address_space(3))) unsigned int*)(l), 16, 0, 0)

__global__ __launch_bounds__(256) void gemm_mi_kernel(const unsigned char* __restrict__ A,
                                                      const unsigned char* __restrict__ B,
                                                      float* __restrict__ S_out) {
    __shared__ __align__(16) unsigned char As[128 * 64];   // 8 KB: 128 rows x 64B (BK=64 fp8)
    __shared__ __align__(16) unsigned char Bs[128 * 64];
    const int t = threadIdx.x;
    const int m0 = blockIdx.x * 128, n0 = blockIdx.y * 128;
    // staging: thread t moves 16B; LDS fill order == t*16 (global_load_lds rule)
    const int sr = t >> 2;          // row 0..63
    const int sk = (t & 3) * 16;    // k byte offset
    const unsigned char* ga0 = A + (size_t)(m0 + sr) * KDIM + sk;
    const unsigned char* ga1 = ga0 + (size_t)64 * KDIM;
    const unsigned char* gb0 = B + (size_t)(n0 + sr) * KDIM + sk;
    const unsigned char* gb1 = gb0 + (size_t)64 * KDIM;
    unsigned char* lA0 = &As[t * 16];
    unsigned char* lA1 = &As[4096 + t * 16];
    unsigned char* lB0 = &Bs[t * 16];
    unsigned char* lB1 = &Bs[4096 + t * 16];
    const int lane = t & 63, wave = t >> 6;
    const int wm = (wave & 1) * 64, wn = (wave >> 1) * 64;   // wave tile 64x64
    const int fr = lane & 31, half = lane >> 5;
    // A/B fragment rule (identical for both operands -> K-order errors cancel):
    // lane supplies 32 bytes: row = tile + fr, k bytes (half*32 .. +31)
    const unsigned char* pA = &As[(wm + fr) * 64 + half * 32];
    const unsigned char* pB = &Bs[(wn + fr) * 64 + half * 32];
    f32x16 acc[2][2];
#pragma unroll
    for (int i = 0; i < 2; i++)
#pragma unroll
        for (int j = 0; j < 2; j++)
#pragma unroll
            for (int r = 0; r < 16; r++) acc[i][j][r] = 0.f;

    for (int k0 = 0; k0 < KDIM; k0 += 64) {
        GLD16(ga0 + k0, lA0);
        GLD16(ga1 + k0, lA1);
        GLD16(gb0 + k0, lB0);
        GLD16(gb1 + k0, lB1);
        __syncthreads();   // drains vmcnt before barrier (m97 semantics)
        v8i af[2], bg[2];
        af[0] = *(const v8i*)(pA);
        af[1] = *(const v8i*)(pA + 32 * 64);
        bg[0] = *(const v8i*)(pB);
        bg[1] = *(const v8i*)(pB + 32 * 64);
#pragma unroll
        for (int i = 0; i < 2; i++)
#pragma unroll
            for (int j = 0; j < 2; j++)
                acc[i][j] = __builtin_amdgcn_mfma_scale_f32_32x32x64_f8f6f4(
                    af[i], bg[j], acc[i][j], 0 /*A=fp8*/, 0 /*B=fp8*/,
                    0, 0x7f /*scaleA e8m0=1.0*/, 0, 0x7f /*scaleB*/);
        __syncthreads();
    }
    // epilogue: acc = 512^2 * N * joint -> joint = acc * 2^-31. Global sum.
    const float invS = 4.656612873077393e-10f;   // 2^-31
    float loc = 0.f;
#pragma unroll
    for (int i = 0; i < 2; i++)
#pragma unroll
        for (int j = 0; j < 2; j++)
#pragma unroll
            for (int r = 0; r < 16; r++) {
                float v = acc[i][j][r] * invS;
                loc += v * __logf(v + EPS);
            }
    loc = wave_sum(loc);
    __shared__ float sred[4];
    if (lane == 0) sred[wave] = loc;
    __syncthreads();
    if (t == 0) atomicAdd(S_out, sred[0] + sred[1] + sred[2] + sred[3]);
}

// ---------------------------------------------------------------------------
// Kernel 4: finalize. entropy = Σ entPart / N;
// MI = S_jlogj - Σ mX log(mX+eps) - Σ mY log(mY+eps); marg scale 2^-22.
// ---------------------------------------------------------------------------
__global__ __launch_bounds__(256) void finalize_kernel(const float* __restrict__ accums,
                                                       const float* __restrict__ entPart,
                                                       const float* __restrict__ margX,
                                                       const float* __restrict__ margY,
                                                       float* __restrict__ out) {
    const int t = threadIdx.x;
    const int lane = t & 63, w = t >> 6;
    const float invN = 1.0f / 8192.0f;
    const float invM = 1.0f / 4194304.0f;   // 1/(512*8192) = 2^-22
    float sx = 0.f, sy = 0.f, se = 0.f;
    for (int c = t; c < CDIM; c += 256) {
        float mx = margX[c] * invM;
        float my = margY[c] * invM;
        sx += mx * __logf(mx + EPS);
        sy += my * __logf(my + EPS);
    }
    for (int c = t; c < 2048; c += 256) se += entPart[c];
    sx = wave_sum(sx); sy = wave_sum(sy); se = wave_sum(se);
    __shared__ float rx[4], ry[4], re[4];
    if (lane == 0) { rx[w] = sx; ry[w] = sy; re[w] = se; }
    __syncthreads();
    if (t == 0) {
        float SX = rx[0] + rx[1] + rx[2] + rx[3];
        float SY = ry[0] + ry[1] + ry[2] + ry[3];
        float SE = re[0] + re[1] + re[2] + re[3];
        out[0] = SE * invN;                 // mean entropy
        out[1] = accums[0] - SX - SY;       // MI
    }
}

// ---------------------------------------------------------------------------
// Workspace layout (bytes):
//   0         PXT  fp8 [4096][8192]    33554432
//   33554432  PYT  fp8 [4096][8192]    33554432
//   67108864  statsX float2[8192]         65536
//   67174400  statsY float2[8192]         65536
//   67239936  margX  f32[4096]            16384
//   67256320  margY  f32[4096]            16384
//   67272704  accums f32[0]=S_jlogj         256
//   67272960  entPart f32[2048]            8192
// ---------------------------------------------------------------------------
extern "C" void kernel_launch(void* const* d_in, const int* in_sizes, int n_in,
                              void* d_out, int out_size, void* d_ws, size_t ws_size,
                              hipStream_t stream) {
    const float* X = (const float*)d_in[0];
    const float* Y = (const float*)d_in[1];
    char* ws = (char*)d_ws;
    unsigned char* PXT = (unsigned char*)ws;
    unsigned char* PYT = (unsigned char*)(ws + 33554432ll);
    float2* statsX = (float2*)(ws + 67108864ll);
    float2* statsY = (float2*)(ws + 67174400ll);
    float* margX = (float*)(ws + 67239936ll);
    float* margY = (float*)(ws + 67256320ll);
    float* accums = (float*)(ws + 67272704ll);
    float* entPart = (float*)(ws + 67272960ll);

    // zero margins + accumulators (ws is poisoned 0xAA before every launch)
    hipMemsetAsync(ws + 67239936ll, 0, 2 * 16384 + 256, stream);

    row_stats_kernel<<<dim3(2048, 2), 256, 0, stream>>>(X, Y, statsX, statsY, entPart);
    norm_transpose_kernel<<<dim3(CDIM / 64, NROWS / 64, 2), 256, 0, stream>>>(
        X, Y, statsX, statsY, PXT, PYT, margX, margY);
    gemm_mi_kernel<<<dim3(CDIM / 128, CDIM / 128), 256, 0, stream>>>(PXT, PYT, &accums[0]);
    finalize_kernel<<<1, 256, 0, stream>>>(accums, entPart, margX, margY, (float*)d_out);
}

// Round 4
// 484.910 us; speedup vs baseline: 1.7913x; 1.1151x over previous
//
#include <hip/hip_runtime.h>
#include <hip/hip_bf16.h>
#include <stdint.h>

// Problem constants (N=8192 rows, C=4096 classes; reduction dim of joint GEMM = N)
#define NROWS 8192
#define CDIM  4096
#define KDIM  8192
#define EPS   1e-12f

typedef __attribute__((ext_vector_type(8)))  int   v8i;     // 32 fp8 bytes (8 VGPRs)
typedef __attribute__((ext_vector_type(4)))  float f32x4;
typedef __attribute__((ext_vector_type(2)))  float f32x2;

// Butterfly reductions: all lanes end with the result.
__device__ inline float wave_sum(float v) {
#pragma unroll
    for (int o = 32; o > 0; o >>= 1) v += __shfl_xor(v, o, 64);
    return v;
}
__device__ inline float wave_max(float v) {
#pragma unroll
    for (int o = 32; o > 0; o >>= 1) v = fmaxf(v, __shfl_xor(v, o, 64));
    return v;
}

// ---------------------------------------------------------------------------
// Pass 1: wave-per-row softmax stats + entropy + fp8 quantized row-major write.
// Row (4096 f32 = 16 KB) lives in 64 VGPRs/lane; butterfly reductions; the
// normalized probs are quantized fp8(512*p) and stored [N][C] with coalesced
// dword stores. No stats arrays, no second f32 read, no exp recompute.
// entropy_n = max + lnZ - (sum e^{x-max} * x)/Z. grid=(2048,2): y=1 -> Y.
// ---------------------------------------------------------------------------
__global__ __launch_bounds__(256) void row_quant_kernel(const float* __restrict__ X,
                                                        const float* __restrict__ Y,
                                                        unsigned char* __restrict__ QX,
                                                        unsigned char* __restrict__ QY,
                                                        float* __restrict__ entPart) {
    const int t = threadIdx.x, lane = t & 63, wave = t >> 6;
    const int row = blockIdx.x * 4 + wave;
    const bool isY = blockIdx.y != 0;
    const float4* s4 = (const float4*)((isY ? Y : X) + (size_t)row * CDIM);
    unsigned int* dst = (unsigned int*)((isY ? QY : QX) + (size_t)row * CDIM);
    float4 v[16];
#pragma unroll
    for (int i = 0; i < 16; i++) v[i] = s4[i * 64 + lane];
    float m = -3.0e38f;
#pragma unroll
    for (int i = 0; i < 16; i++)
        m = fmaxf(m, fmaxf(fmaxf(v[i].x, v[i].y), fmaxf(v[i].z, v[i].w)));
    m = wave_max(m);
    float Z = 0.f, S = 0.f;
#pragma unroll
    for (int i = 0; i < 16; i++) {
        float e;
        e = __expf(v[i].x - m); Z += e; S += e * v[i].x; v[i].x = e;
        e = __expf(v[i].y - m); Z += e; S += e * v[i].y; v[i].y = e;
        e = __expf(v[i].z - m); Z += e; S += e * v[i].z; v[i].z = e;
        e = __expf(v[i].w - m); Z += e; S += e * v[i].w; v[i].w = e;
    }
    Z = wave_sum(Z); S = wave_sum(S);
    __shared__ float sent[4];
    if (lane == 0) sent[wave] = m + __logf(Z) - S / Z;
    // quantize: q = fp8(512 * e / Z). 512*p_max ~ 4 << 448 (e4m3 max) -> safe.
    const float sc = 512.0f / Z;
#pragma unroll
    for (int i = 0; i < 16; i++) {
        unsigned int w0 = (unsigned int)__builtin_amdgcn_cvt_pk_fp8_f32(
            v[i].x * sc, v[i].y * sc, 0, false);
        w0 = (unsigned int)__builtin_amdgcn_cvt_pk_fp8_f32(
            v[i].z * sc, v[i].w * sc, (int)w0, true);
        dst[i * 64 + lane] = w0;   // 64 lanes x 4B contiguous = 256B/instr
    }
    __syncthreads();
    if (t == 0 && !isY)
        entPart[blockIdx.x] = sent[0] + sent[1] + sent[2] + sent[3];
}

// ---------------------------------------------------------------------------
// Pass 2: fp8 [N][C] -> [C][N] transpose, 128x128 byte tiles, fully in-register
// via v_perm 4x4 byte micro-transpose (no LDS tile, no scalar LDS reads).
// Margins (sum over n of dequantized fp8, per class) fused: LDS partial +
// one global atomic per class per block (524k atomics over 4096 addresses).
// grid = (32, 64, 2): x=c-tile, y=n-tile, z selects X/Y.
// ---------------------------------------------------------------------------
__global__ __launch_bounds__(256) void transpose_marg_kernel(
        const unsigned char* __restrict__ QX, const unsigned char* __restrict__ QY,
        unsigned char* __restrict__ QXT, unsigned char* __restrict__ QYT,
        float* __restrict__ margX, float* __restrict__ margY) {
    const bool isY = blockIdx.z != 0;
    const unsigned char* __restrict__ Q = isY ? QY : QX;
    unsigned char* __restrict__ QT = isY ? QYT : QXT;
    float* __restrict__ marg = isY ? margY : margX;

    __shared__ float smarg[128];
    const int t = threadIdx.x;
    const int c0 = blockIdx.x * 128, n0 = blockIdx.y * 128;
    if (t < 128) smarg[t] = 0.f;
    __syncthreads();
    const int cq = (t & 31) * 4;   // class offset within tile (x4)
    const int nq = (t >> 5) * 16;  // n offset within tile (x16)
    const unsigned char* src = Q + (size_t)(n0 + nq) * CDIM + c0 + cq;
    unsigned int u[16];
#pragma unroll
    for (int i = 0; i < 16; i++)
        u[i] = *(const unsigned int*)(src + (size_t)i * CDIM);  // 2 rows x 128B per instr
    // 4x4 byte micro-transpose: d[j][k] = n-consecutive bytes for class cq+j
#pragma unroll
    for (int j = 0; j < 4; j++) {
        const unsigned int sel = (unsigned)j | ((unsigned)(j + 4) << 8);
        unsigned int d0, d1, d2, d3;
        {
            unsigned int p01 = __builtin_amdgcn_perm(u[1], u[0], sel);
            unsigned int p23 = __builtin_amdgcn_perm(u[3], u[2], sel);
            d0 = __builtin_amdgcn_perm(p23, p01, 0x05040100u);
        }
        {
            unsigned int p01 = __builtin_amdgcn_perm(u[5], u[4], sel);
            unsigned int p23 = __builtin_amdgcn_perm(u[7], u[6], sel);
            d1 = __builtin_amdgcn_perm(p23, p01, 0x05040100u);
        }
        {
            unsigned int p01 = __builtin_amdgcn_perm(u[9], u[8], sel);
            unsigned int p23 = __builtin_amdgcn_perm(u[11], u[10], sel);
            d2 = __builtin_amdgcn_perm(p23, p01, 0x05040100u);
        }
        {
            unsigned int p01 = __builtin_amdgcn_perm(u[13], u[12], sel);
            unsigned int p23 = __builtin_amdgcn_perm(u[15], u[14], sel);
            d3 = __builtin_amdgcn_perm(p23, p01, 0x05040100u);
        }
        uint4 o; o.x = d0; o.y = d1; o.z = d2; o.w = d3;
        *(uint4*)(QT + (size_t)(c0 + cq + j) * KDIM + n0 + nq) = o;
        // margin partial: dequant-sum the 16 fp8 values (same bytes GEMM reads)
        float s = 0.f;
        f32x2 a;
        a = __builtin_amdgcn_cvt_pk_f32_fp8((int)d0, false); s += a.x + a.y;
        a = __builtin_amdgcn_cvt_pk_f32_fp8((int)d0, true);  s += a.x + a.y;
        a = __builtin_amdgcn_cvt_pk_f32_fp8((int)d1, false); s += a.x + a.y;
        a = __builtin_amdgcn_cvt_pk_f32_fp8((int)d1, true);  s += a.x + a.y;
        a = __builtin_amdgcn_cvt_pk_f32_fp8((int)d2, false); s += a.x + a.y;
        a = __builtin_amdgcn_cvt_pk_f32_fp8((int)d2, true);  s += a.x + a.y;
        a = __builtin_amdgcn_cvt_pk_f32_fp8((int)d3, false); s += a.x + a.y;
        a = __builtin_amdgcn_cvt_pk_f32_fp8((int)d3, true);  s += a.x + a.y;
        atomicAdd(&smarg[cq + j], s);
    }
    __syncthreads();
    if (t < 128) atomicAdd(&marg[c0 + t], smarg[t]);
}

// ---------------------------------------------------------------------------
// Pass 3: joint GEMM, MX-fp8 16x16x128 (m148 pattern: BK=128, 16 MFMA + 8
// GLD16 per barrier-pair), fused epilogue sum j*log(j+eps). Global-sum
// epilogue + identical A/B fragment rule -> layout/K-order errors cancel.
// ---------------------------------------------------------------------------
#define GLD16(g, l)                                                                   \
    __builtin_amdgcn_global_load_lds((const __attribute__((address_space(1))) unsigned int*)(g), \
                                     (__attribute__((address_space(3))) unsigned int*)(l), 16, 0, 0)

__global__ __launch_bounds__(256) void gemm_mi_kernel(const unsigned char* __restrict__ A,
                                                      const unsigned char* __restrict__ B,
                                                      float* __restrict__ S_out) {
    __shared__ __align__(16) unsigned char As[128 * 128];   // 16 KB: 128 rows x 128B (BK=128)
    __shared__ __align__(16) unsigned char Bs[128 * 128];
    const int t = threadIdx.x;
    const int m0 = blockIdx.x * 128, n0 = blockIdx.y * 128;
    // staging: 4 GLD16 per matrix per thread; instr i of wave w fills LDS
    // rows [w*32+i*8, +8) x 128B contiguously in lane order (global_load_lds rule)
    const int grow = (t >> 6) * 32 + ((t & 63) >> 3);   // row this lane sources
    const int gcol = (t & 7) * 16;                      // 8 lanes x 16B = 128B per row
    const unsigned char* ga = A + (size_t)(m0 + grow) * KDIM + gcol;
    const unsigned char* gb = B + (size_t)(n0 + grow) * KDIM + gcol;
    unsigned char* la = &As[(t >> 6) * 4096 + (t & 63) * 16];
    unsigned char* lb = &Bs[(t >> 6) * 4096 + (t & 63) * 16];
    const int lane = t & 63, wave = t >> 6;
    const int wm = (wave & 1) * 64, wn = (wave >> 1) * 64;   // wave tile 64x64
    const int fr = lane & 15, quad = lane >> 4;
    // fragment rule (same for A and B): row = tile+fr, k bytes quad*32..+31
    const unsigned char* pA = &As[(wm + fr) * 128 + quad * 32];
    const unsigned char* pB = &Bs[(wn + fr) * 128 + quad * 32];
    f32x4 acc[4][4];
#pragma unroll
    for (int i = 0; i < 4; i++)
#pragma unroll
        for (int j = 0; j < 4; j++) { acc[i][j][0] = 0.f; acc[i][j][1] = 0.f; acc[i][j][2] = 0.f; acc[i][j][3] = 0.f; }

    for (int k0 = 0; k0 < KDIM; k0 += 128) {
#pragma unroll
        for (int i = 0; i < 4; i++) {
            GLD16(ga + (size_t)i * 8 * KDIM + k0, la + i * 1024);
            GLD16(gb + (size_t)i * 8 * KDIM + k0, lb + i * 1024);
        }
        __syncthreads();   // drains vmcnt before barrier (m97 semantics)
        v8i af[4], bg[4];
#pragma unroll
        for (int i = 0; i < 4; i++) af[i] = *(const v8i*)(pA + i * 16 * 128);
#pragma unroll
        for (int j = 0; j < 4; j++) bg[j] = *(const v8i*)(pB + j * 16 * 128);
#pragma unroll
        for (int i = 0; i < 4; i++)
#pragma unroll
            for (int j = 0; j < 4; j++)
                acc[i][j] = __builtin_amdgcn_mfma_scale_f32_16x16x128_f8f6f4(
                    af[i], bg[j], acc[i][j], 0 /*A=fp8*/, 0 /*B=fp8*/,
                    0, 0x7f /*scaleA e8m0=1.0*/, 0, 0x7f /*scaleB*/);
        __syncthreads();
    }
    // epilogue: acc = 512^2 * N * joint -> joint = acc * 2^-31. Global sum.
    const float invS = 4.656612873077393e-10f;   // 2^-31
    float loc = 0.f;
#pragma unroll
    for (int i = 0; i < 4; i++)
#pragma unroll
        for (int j = 0; j < 4; j++)
#pragma unroll
            for (int r = 0; r < 4; r++) {
                float v = acc[i][j][r] * invS;
                loc += v * __logf(v + EPS);
            }
    loc = wave_sum(loc);
    __shared__ float sred[4];
    if (lane == 0) sred[wave] = loc;
    __syncthreads();
    if (t == 0) atomicAdd(S_out, sred[0] + sred[1] + sred[2] + sred[3]);
}

// ---------------------------------------------------------------------------
// Pass 4: finalize. entropy = sum entPart / N;
// MI = S_jlogj - sum mX log(mX+eps) - sum mY log(mY+eps); marg scale 2^-22.
// ---------------------------------------------------------------------------
__global__ __launch_bounds__(256) void finalize_kernel(const float* __restrict__ accums,
                                                       const float* __restrict__ entPart,
                                                       const float* __restrict__ margX,
                                                       const float* __restrict__ margY,
                                                       float* __restrict__ out) {
    const int t = threadIdx.x;
    const int lane = t & 63, w = t >> 6;
    const float invN = 1.0f / 8192.0f;
    const float invM = 1.0f / 4194304.0f;   // 1/(512*8192) = 2^-22
    float sx = 0.f, sy = 0.f, se = 0.f;
    for (int c = t; c < CDIM; c += 256) {
        float mx = margX[c] * invM;
        float my = margY[c] * invM;
        sx += mx * __logf(mx + EPS);
        sy += my * __logf(my + EPS);
    }
    for (int c = t; c < 2048; c += 256) se += entPart[c];
    sx = wave_sum(sx); sy = wave_sum(sy); se = wave_sum(se);
    __shared__ float rx[4], ry[4], re[4];
    if (lane == 0) { rx[w] = sx; ry[w] = sy; re[w] = se; }
    __syncthreads();
    if (t == 0) {
        float SX = rx[0] + rx[1] + rx[2] + rx[3];
        float SY = ry[0] + ry[1] + ry[2] + ry[3];
        float SE = re[0] + re[1] + re[2] + re[3];
        out[0] = SE * invN;                 // mean entropy
        out[1] = accums[0] - SX - SY;       // MI
    }
}

// ---------------------------------------------------------------------------
// Workspace layout (bytes):
//   0          QX   fp8 [8192][4096]   33554432   (row-major probs x512)
//   33554432   QY   fp8 [8192][4096]   33554432
//   67108864   QXT  fp8 [4096][8192]   33554432   (transposed, GEMM operand)
//   100663296  QYT  fp8 [4096][8192]   33554432
//   134217728  margX f32[4096]            16384
//   134234112  margY f32[4096]            16384
//   134250496  accums f32[0]=S_jlogj        256
//   134250752  entPart f32[2048]           8192
// ---------------------------------------------------------------------------
extern "C" void kernel_launch(void* const* d_in, const int* in_sizes, int n_in,
                              void* d_out, int out_size, void* d_ws, size_t ws_size,
                              hipStream_t stream) {
    const float* X = (const float*)d_in[0];
    const float* Y = (const float*)d_in[1];
    char* ws = (char*)d_ws;
    unsigned char* QX  = (unsigned char*)ws;
    unsigned char* QY  = (unsigned char*)(ws + 33554432ll);
    unsigned char* QXT = (unsigned char*)(ws + 67108864ll);
    unsigned char* QYT = (unsigned char*)(ws + 100663296ll);
    float* margX = (float*)(ws + 134217728ll);
    float* margY = (float*)(ws + 134234112ll);
    float* accums = (float*)(ws + 134250496ll);
    float* entPart = (float*)(ws + 134250752ll);

    // zero margins + accumulators (ws is poisoned 0xAA before every launch)
    hipMemsetAsync(ws + 134217728ll, 0, 2 * 16384 + 256, stream);

    row_quant_kernel<<<dim3(2048, 2), 256, 0, stream>>>(X, Y, QX, QY, entPart);
    transpose_marg_kernel<<<dim3(CDIM / 128, NROWS / 128, 2), 256, 0, stream>>>(
        QX, QY, QXT, QYT, margX, margY);
    gemm_mi_kernel<<<dim3(CDIM / 128, CDIM / 128), 256, 0, stream>>>(QXT, QYT, &accums[0]);
    finalize_kernel<<<1, 256, 0, stream>>>(accums, entPart, margX, margY, (float*)d_out);
}